// Round 9
// baseline (268.210 us; speedup 1.0000x reference)
//
#include <hip/hip_runtime.h>

// LearnedSegmentEncoder on MI355X — linear bf16 downcast + paired-tile MFMA GEMM.
// B=8, C=128, P=65536, D=64, S=32.
// Identity: pooled = conv2_w @ mean_seg(relu(conv1_w@x+b1)) + b2 (conv2 hoisted
// past the segment mean), so only conv1 runs per-pixel.
// Pass 1: feat fp32 -> bf16, pure linear stream (m13 copy shape, ~6 TB/s).
// Pass 2: R2-structure GEMM on bf16: one dword load = 2 pixels (even px ->
// tile-A, odd px -> tile-B), halving strided bytes AND instructions/pixel;
// no barriers in the loop, no LDS staging of x, 16 waves/CU.

#define B_ 8
#define C_ 128
#define P_ 65536
#define D_ 64
#define S_ 32

typedef short bf16x8 __attribute__((ext_vector_type(8)));
typedef float f32x4  __attribute__((ext_vector_type(4)));

__device__ __forceinline__ unsigned f2bfu(float f) {
  union { float f; unsigned u; } v; v.f = f;
  return (v.u + 0x7fffu + ((v.u >> 16) & 1u)) >> 16;   // RNE
}
__device__ __forceinline__ short f2bf(float f) { return (short)f2bfu(f); }

__global__ __launch_bounds__(256) void w1_to_bf16(const float* __restrict__ w1,
                                                  short* __restrict__ wbf) {
  int i = blockIdx.x * 256 + threadIdx.x;
  if (i < C_ * D_) wbf[i] = f2bf(w1[i]);
}

// Pure linear stream: 64M floats -> 64M bf16. Grid-stride, float4 in, uint4 out.
__global__ __launch_bounds__(256) void feat_to_bf16(const float4* __restrict__ in,
                                                    uint4* __restrict__ out) {
  const int n = (B_ * C_ * P_) / 8;                    // uint4-chunks (8 bf16)
  const int stride = gridDim.x * 256;
  for (int i = blockIdx.x * 256 + threadIdx.x; i < n; i += stride) {
    const float4 a = in[2 * i], b = in[2 * i + 1];
    uint4 o;
    o.x = f2bfu(a.x) | (f2bfu(a.y) << 16);
    o.y = f2bfu(a.z) | (f2bfu(a.w) << 16);
    o.z = f2bfu(b.x) | (f2bfu(b.y) << 16);
    o.w = f2bfu(b.z) | (f2bfu(b.w) << 16);
    out[i] = o;
  }
}

// Grid (P/512, B) = (128, 8) = 1024 blocks (4/CU), 256 thr = 4 waves.
// Wave owns 128 px as 4 tile-PAIRS of 32 px: even px -> tile-A, odd -> tile-B.
// PACKED: one u32 load = bf16 pair {px 2m, 2m+1} feeding both tiles' A-frags.
template<bool PACKED>
__global__ __launch_bounds__(256, 4) void proj_mfma(
    const int* __restrict__ labels, const float* __restrict__ featf,
    const unsigned* __restrict__ featb, const short* __restrict__ wbf,
    const float* __restrict__ b1, float* __restrict__ gsum,
    int* __restrict__ gcnt)
{
  __shared__ float s_acc[S_][68];                      // 8.5 KB
  __shared__ int   s_cnt[S_];

  const int tid = threadIdx.x;
  const int wave = tid >> 6, l = tid & 63, m = l & 15, g = l >> 4;
  const int b   = blockIdx.y;
  const int px0 = blockIdx.x * 512 + wave * 128;

  for (int i = tid; i < S_ * 68; i += 256) ((float*)s_acc)[i] = 0.f;
  if (tid < S_) s_cnt[tid] = 0;
  __syncthreads();

  // W1^T B-fragments (held in regs; reloads, if the allocator trims, are L2-hit)
  bf16x8 bfr[4][4];
  #pragma unroll
  for (int nt = 0; nt < 4; ++nt)
    #pragma unroll
    for (int ks = 0; ks < 4; ++ks)
      bfr[nt][ks] = *(const bf16x8*)&wbf[(nt * 16 + m) * C_ + ks * 32 + g * 8];
  float b1v[4];
  #pragma unroll
  for (int nt = 0; nt < 4; ++nt) b1v[nt] = b1[nt * 16 + m];

  const int* lb = labels + (size_t)b * P_;

  for (int it = 0; it < 4; ++it) {
    const int pp = px0 + it * 32;                      // tile-pair base (32 px)
    f32x4 aA[4], aB[4];
    #pragma unroll
    for (int nt = 0; nt < 4; ++nt) {
      aA[nt] = (f32x4){0.f, 0.f, 0.f, 0.f};
      aB[nt] = (f32x4){0.f, 0.f, 0.f, 0.f};
    }

    #pragma unroll
    for (int ks = 0; ks < 4; ++ks) {
      bf16x8 afA, afB;
      if (PACKED) {
        const unsigned* xp = featb
            + ((size_t)b * C_ + ks * 32 + g * 8) * (P_ / 2) + (pp >> 1) + m;
        #pragma unroll
        for (int j = 0; j < 8; ++j) {
          const unsigned v = xp[(size_t)j * (P_ / 2)];
          afA[j] = (short)(v & 0xffffu);               // even pixel
          afB[j] = (short)(v >> 16);                   // odd pixel
        }
      } else {
        const float* xp = featf
            + ((size_t)b * C_ + ks * 32 + g * 8) * P_ + pp + 2 * m;
        #pragma unroll
        for (int j = 0; j < 8; ++j) {
          afA[j] = f2bf(xp[(size_t)j * P_]);
          afB[j] = f2bf(xp[(size_t)j * P_ + 1]);
        }
      }
      #pragma unroll
      for (int nt = 0; nt < 4; ++nt) {
        aA[nt] = __builtin_amdgcn_mfma_f32_16x16x32_bf16(afA, bfr[nt][ks], aA[nt], 0, 0, 0);
        aB[nt] = __builtin_amdgcn_mfma_f32_16x16x32_bf16(afB, bfr[nt][ks], aB[nt], 0, 0, 0);
      }
    }

    // C/D: d = nt*16 + m, row g*4+r -> pixels pp + 2*(g*4+r) (A) / +1 (B)
    #pragma unroll
    for (int r = 0; r < 4; ++r) {
      const int2 lv = *(const int2*)&lb[pp + 2 * (g * 4 + r)];
      const int lA = lv.x & (S_ - 1), lB = lv.y & (S_ - 1);
      #pragma unroll
      for (int nt = 0; nt < 4; ++nt) {
        atomicAdd(&s_acc[lA][nt * 16 + m], fmaxf(aA[nt][r] + b1v[nt], 0.f));
        atomicAdd(&s_acc[lB][nt * 16 + m], fmaxf(aB[nt][r] + b1v[nt], 0.f));
      }
    }
    if (m < 4) {
      const int2 lv = *(const int2*)&lb[pp + 2 * (g * 4 + m)];
      atomicAdd(&s_cnt[lv.x & (S_ - 1)], 1);
      atomicAdd(&s_cnt[lv.y & (S_ - 1)], 1);
    }
  }

  __syncthreads();
  for (int i = tid; i < S_ * D_; i += 256)
    atomicAdd(&gsum[(size_t)b * S_ * D_ + i], s_acc[i >> 6][i & 63]);
  if (tid < S_) atomicAdd(&gcnt[b * S_ + tid], s_cnt[tid]);
}

// Grid (S, B), 64 lanes: all (b,s) blocks independent; ballot-based rank.
__global__ __launch_bounds__(64) void seg_finalize2(
    const float* __restrict__ gsum, const int* __restrict__ gcnt,
    const float* __restrict__ w2, const float* __restrict__ b2,
    const float* __restrict__ emb, const float* __restrict__ wo,
    const float* __restrict__ bo, float* __restrict__ out)
{
  const int s = blockIdx.x, b = blockIdx.y, o = threadIdx.x;
  const int co = (o < S_) ? gcnt[b * S_ + o] : 0;
  const unsigned long long mask = __ballot(co > 0);
  const int cnt = gcnt[b * S_ + s];
  if (cnt <= 0) return;                               // uniform exit
  const int rank = __popcll(mask & ((1ull << s) - 1ull));

  __shared__ float s_mean[D_], s_pool[D_];
  s_mean[o] = gsum[((size_t)b * S_ + s) * D_ + o] * (1.f / (float)cnt);
  __syncthreads();
  float pooled = b2[o];
  #pragma unroll
  for (int d = 0; d < D_; ++d) pooled += w2[o * D_ + d] * s_mean[d];
  s_pool[o] = pooled;
  __syncthreads();
  float r = bo[o];
  #pragma unroll
  for (int e = 0; e < D_; ++e) r += wo[o * 2 * D_ + e] * s_pool[e];
  #pragma unroll
  for (int e = 0; e < D_; ++e) r += wo[o * 2 * D_ + D_ + e] * emb[s * D_ + e];
  out[((size_t)b * S_ + rank) * D_ + o] = r;
}

extern "C" void kernel_launch(void* const* d_in, const int* in_sizes, int n_in,
                              void* d_out, int out_size, void* d_ws, size_t ws_size,
                              hipStream_t stream) {
  const int*   labels = (const int*)  d_in[0];
  const float* feat   = (const float*)d_in[1];
  const float* w1     = (const float*)d_in[2];
  const float* b1     = (const float*)d_in[3];
  const float* w2     = (const float*)d_in[4];
  const float* b2     = (const float*)d_in[5];
  const float* emb    = (const float*)d_in[6];
  const float* wo     = (const float*)d_in[7];
  const float* bo     = (const float*)d_in[8];
  float* out = (float*)d_out;

  // ws layout: gsum | gcnt | wbf | xbf(128 MB, optional)
  char* w = (char*)d_ws;
  float*    gsum = (float*)w;    w += (size_t)B_ * S_ * D_ * 4;
  int*      gcnt = (int*)w;      w += (size_t)B_ * S_ * 4;
  short*    wbf  = (short*)w;    w += (size_t)C_ * D_ * 2;
  unsigned* xbf  = (unsigned*)w; w += (size_t)B_ * C_ * P_ * 2;
  const bool packed = ((size_t)(w - (char*)d_ws) <= ws_size);

  hipMemsetAsync(d_ws, 0, (size_t)B_ * S_ * D_ * 4 + (size_t)B_ * S_ * 4, stream);
  hipMemsetAsync(d_out, 0, (size_t)out_size * sizeof(float), stream);

  w1_to_bf16<<<(C_ * D_ + 255) / 256, 256, 0, stream>>>(w1, wbf);

  dim3 grid(P_ / 512, B_);
  if (packed) {
    feat_to_bf16<<<2048, 256, 0, stream>>>((const float4*)feat, (uint4*)xbf);
    proj_mfma<true><<<grid, 256, 0, stream>>>(labels, feat, xbf, wbf, b1, gsum, gcnt);
  } else {
    proj_mfma<false><<<grid, 256, 0, stream>>>(labels, feat, xbf, wbf, b1, gsum, gcnt);
  }
  seg_finalize2<<<dim3(S_, B_), 64, 0, stream>>>(gsum, gcnt, w2, b2, emb, wo, bo, out);
}